// Round 17
// baseline (198.508 us; speedup 1.0000x reference)
//
#include <hip/hip_runtime.h>

#define Bn 16
#define Qn 128
#define Kn 128
#define Dn 512
#define Hn 512
#define NEGV (-3.0e38f)
// 2*log2(e): exp2(PSCALE*x) == e^{2x}
#define PSCALE 2.8853900817779268f

#define REP_PROJ 8
#define REP_SCORE 5
#define REP_SAV 8

typedef short s16x8 __attribute__((ext_vector_type(8)));
typedef float f32x4 __attribute__((ext_vector_type(4)));

__device__ __forceinline__ float exp2_hw(float x) {
  float r;
  asm("v_exp_f32 %0, %1" : "=v"(r) : "v"(x));
  return r;
}
__device__ __forceinline__ float rcp_hw(float x) { return __builtin_amdgcn_rcpf(x); }
__device__ __forceinline__ unsigned short f2bf(float f) {   // RNE f32->bf16
  unsigned int u = __float_as_uint(f);
  u += 0x7fff + ((u >> 16) & 1);
  return (unsigned short)(u >> 16);
}
__device__ __forceinline__ unsigned int pack2bf(float lo, float hi) {
  return (unsigned int)f2bf(lo) | ((unsigned int)f2bf(hi) << 16);
}
__device__ __forceinline__ float bfl(unsigned int u) { return __uint_as_float(u << 16); }
__device__ __forceinline__ float bfh(unsigned int u) { return __uint_as_float(u & 0xffff0000u); }

// ---------- K1: W transpose + bf16: Wt[2][512 n][512 k] ----------
__global__ __launch_bounds__(256) void convert_w(
    const float* __restrict__ Wq, const float* __restrict__ Wk,
    unsigned short* __restrict__ Wt)
{
  const int tid = blockIdx.x * 256 + threadIdx.x;     // 0..32767
  const int n = tid & 511, rest = tid >> 9;           // rest 0..63
  const int sel = rest >> 5, k16 = rest & 31;
  const float* W = sel ? Wk : Wq;
  unsigned short o[16];
  #pragma unroll
  for (int i = 0; i < 16; ++i)
    o[i] = f2bf(W[(size_t)(k16 * 16 + i) * Hn + n]);
  unsigned short* dst = Wt + (size_t)sel * 262144 + (size_t)n * 512 + k16 * 16;
  #pragma unroll
  for (int j = 0; j < 4; ++j) *(ushort4*)(dst + j * 4) = *(ushort4*)&o[j * 4];
}

// ---------- K2: projections (DIAGNOSTIC xREP_PROJ) ----------
__global__ __launch_bounds__(256) void proj_mfma(
    const float* __restrict__ queries, const float* __restrict__ keys,
    const unsigned short* __restrict__ Wt, const float* __restrict__ wv,
    unsigned int* __restrict__ QWp, unsigned int* __restrict__ Ekp)
{
  __shared__ unsigned short Al[64][72];
  __shared__ unsigned short Bl[128][72];
  __shared__ float Tep[64][68];
  const int t = threadIdx.x, w = t >> 6, l = t & 63;
  const int wm = w >> 1, wn = w & 1;
  const int rowTile = blockIdx.x;
  const int n0 = blockIdx.y * 128;
  const int R0 = rowTile * 64;
  const bool isQ = rowTile < 32;
  const float* Asrc = isQ ? queries : keys;
  const int rowBase = isQ ? R0 : (R0 - 2048);
  const unsigned short* Wsel = Wt + (isQ ? 0 : 262144);
  const int lr = l & 15, lk = l >> 4;

  for (int rep = 0; rep < REP_PROJ; ++rep) {
    __syncthreads();
    f32x4 acc[2][4];
    #pragma unroll
    for (int m = 0; m < 2; ++m)
      #pragma unroll
      for (int n = 0; n < 4; ++n) acc[m][n] = (f32x4)0.f;

    for (int k0 = 0; k0 < Hn; k0 += 64) {
      float4 afr[4];
      ushort4 br[4][2];
      #pragma unroll
      for (int i = 0; i < 4; ++i) {
        int g = t + 256 * i, r = g >> 4, c4 = g & 15;
        afr[i] = *(const float4*)(Asrc + (size_t)(rowBase + r) * Dn + k0 + c4 * 4);
      }
      #pragma unroll
      for (int i = 0; i < 4; ++i) {
        int g = t + 256 * i, r = g >> 3, c = g & 7;
        const unsigned short* p = Wsel + (size_t)(n0 + r) * Hn + k0 + c * 8;
        br[i][0] = *(const ushort4*)p; br[i][1] = *(const ushort4*)(p + 4);
      }
      __syncthreads();
      #pragma unroll
      for (int i = 0; i < 4; ++i) {
        int g = t + 256 * i, r = g >> 4, c4 = g & 15;
        ushort4 o = {f2bf(afr[i].x), f2bf(afr[i].y), f2bf(afr[i].z), f2bf(afr[i].w)};
        *(ushort4*)&Al[r][c4 * 4] = o;
      }
      #pragma unroll
      for (int i = 0; i < 4; ++i) {
        int g = t + 256 * i, r = g >> 3, c = g & 7;
        *(ushort4*)&Bl[r][c * 8] = br[i][0]; *(ushort4*)&Bl[r][c * 8 + 4] = br[i][1];
      }
      __syncthreads();
      #pragma unroll
      for (int ks = 0; ks < 2; ++ks) {
        s16x8 af[2], bf_[4];
        #pragma unroll
        for (int m = 0; m < 2; ++m)
          af[m] = *(const s16x8*)&Al[wm * 32 + m * 16 + lr][ks * 32 + lk * 8];
        #pragma unroll
        for (int n = 0; n < 4; ++n)
          bf_[n] = *(const s16x8*)&Bl[wn * 64 + n * 16 + lr][ks * 32 + lk * 8];
        #pragma unroll
        for (int m = 0; m < 2; ++m)
          #pragma unroll
          for (int n = 0; n < 4; ++n)
            acc[m][n] = __builtin_amdgcn_mfma_f32_16x16x32_bf16(af[m], bf_[n], acc[m][n], 0, 0, 0);
      }
      __syncthreads();
    }

    if (isQ) {
      #pragma unroll
      for (int m = 0; m < 2; ++m)
        #pragma unroll
        for (int n = 0; n < 4; ++n)
          #pragma unroll
          for (int r = 0; r < 4; ++r) {
            int row = R0 + wm * 32 + m * 16 + lk * 4 + r;
            int col = n0 + wn * 64 + n * 16 + lr;    // h
            float a = acc[m][n][r];
            float F  = exp2_hw(-PSCALE * a);
            float WF = -2.f * wv[col] * F;
            QWp[(size_t)row * Hn + col] = pack2bf(WF, F);
          }
    } else {
      const int krow0 = R0 - 2048;
      const int bb = krow0 >> 7, kb = krow0 & 127;
      const int hl = t >> 2, kq = (t & 3) * 16;
      #pragma unroll
      for (int hc = 0; hc < 2; ++hc) {
        __syncthreads();
        if (wn == hc) {
          #pragma unroll
          for (int m = 0; m < 2; ++m)
            #pragma unroll
            for (int n = 0; n < 4; ++n)
              #pragma unroll
              for (int r = 0; r < 4; ++r) {
                int row_l = wm * 32 + m * 16 + lk * 4 + r;
                int h_l = n * 16 + lr;
                Tep[h_l][row_l] = exp2_hw(PSCALE * acc[m][n][r]);
              }
        }
        __syncthreads();
        unsigned int* dst = Ekp + (size_t)bb * 32768
                          + (size_t)(n0 + hc * 64 + hl) * 64 + (kb + kq) / 2;
        #pragma unroll
        for (int j = 0; j < 4; ++j) {
          float4 v = *(const float4*)&Tep[hl][kq + j * 4];
          uint2 o = {pack2bf(v.x, v.y), pack2bf(v.z, v.w)};
          *(uint2*)(dst + j * 2) = o;
        }
      }
    }
  }
}

// ---------- helper ----------
__device__ __forceinline__ void term8(float WF0, float F0, float WF1, float F1,
                                      const float ek0[8], const float ek1[8],
                                      float acc[8]) {
  #pragma unroll
  for (int j = 0; j < 8; ++j) {
    float d0 = F0 + ek0[j];
    float d1 = F1 + ek1[j];
    float num = __builtin_fmaf(WF0, d1, WF1 * d0);
    acc[j] = __builtin_fmaf(num, rcp_hw(d0 * d1), acc[j]);
  }
}

// ---------- K3: score partials (DIAGNOSTIC xREP_SCORE) ----------
__global__ __launch_bounds__(256) void score_kernel(
    const unsigned int* __restrict__ QWp, const unsigned int* __restrict__ Ekp,
    float* __restrict__ Sp)
{
  __shared__ unsigned int EkLu[64][68];
  __shared__ unsigned int QWLu[32][68];
  const int id = blockIdx.x;
  const int g = id & 127, qt = id >> 7;
  const int b = g >> 3, hs = g & 7;
  const int t = threadIdx.x, w = t >> 6, l = t & 63;
  const int qp = w * 8 + ((l >> 4) << 1);
  const int ku = (l & 15) * 4;
  const int ka8 = (l & 15) * 8;

  for (int rep = 0; rep < REP_SCORE; ++rep) {
    __syncthreads();
    {
      const uint4* esrc = (const uint4*)(Ekp + (size_t)b * 32768 + (size_t)hs * 4096);
      uint4 er[4];
      #pragma unroll
      for (int i = 0; i < 4; ++i) er[i] = esrc[t + 256 * i];
      uint4 qr[2];
      #pragma unroll
      for (int i = 0; i < 2; ++i) {
        int lin = t + 256 * i, row = lin >> 4, c4 = lin & 15;
        qr[i] = *(const uint4*)(QWp + (size_t)(b * Qn + qt * 32 + row) * Hn + hs * 64 + c4 * 4);
      }
      #pragma unroll
      for (int i = 0; i < 4; ++i) {
        int lin = t + 256 * i, row = lin >> 4, c4 = lin & 15;
        *(uint4*)&EkLu[row][c4 * 4] = er[i];
      }
      #pragma unroll
      for (int i = 0; i < 2; ++i) {
        int lin = t + 256 * i, row = lin >> 4, c4 = lin & 15;
        *(uint4*)&QWLu[row][c4 * 4] = qr[i];
      }
    }
    __syncthreads();

    float acc0[8], acc1[8];
    #pragma unroll
    for (int j = 0; j < 8; ++j) { acc0[j] = 0.f; acc1[j] = 0.f; }

    #pragma unroll 4
    for (int hb = 0; hb < 32; ++hb) {
      uint4 e0 = *(const uint4*)&EkLu[2 * hb][ku];
      uint4 e1 = *(const uint4*)&EkLu[2 * hb + 1][ku];
      uint2 qa = *(const uint2*)&QWLu[qp][hb * 2];
      uint2 qb = *(const uint2*)&QWLu[qp + 1][hb * 2];
      float ek0[8], ek1[8];
      {
        const unsigned int u0[4] = {e0.x, e0.y, e0.z, e0.w};
        const unsigned int u1[4] = {e1.x, e1.y, e1.z, e1.w};
        #pragma unroll
        for (int p = 0; p < 4; ++p) {
          ek0[2 * p] = bfl(u0[p]); ek0[2 * p + 1] = bfh(u0[p]);
          ek1[2 * p] = bfl(u1[p]); ek1[2 * p + 1] = bfh(u1[p]);
        }
      }
      term8(bfl(qa.x), bfh(qa.x), bfl(qa.y), bfh(qa.y), ek0, ek1, acc0);
      term8(bfl(qb.x), bfh(qb.x), bfl(qb.y), bfh(qb.y), ek0, ek1, acc1);
    }

    const int q = qt * 32 + qp;
    size_t sb = (((size_t)hs * Bn + b) * Qn + q) * Kn;
    *(float4*)(Sp + sb + ka8)          = (float4){acc0[0], acc0[1], acc0[2], acc0[3]};
    *(float4*)(Sp + sb + ka8 + 4)      = (float4){acc0[4], acc0[5], acc0[6], acc0[7]};
    *(float4*)(Sp + sb + Kn + ka8)     = (float4){acc1[0], acc1[1], acc1[2], acc1[3]};
    *(float4*)(Sp + sb + Kn + ka8 + 4) = (float4){acc1[4], acc1[5], acc1[6], acc1[7]};
  }
}

// ---------- K4: fused softmax + AV (DIAGNOSTIC xREP_SAV) ----------
__global__ __launch_bounds__(256) void softmax_av(
    const float* __restrict__ Sp, const int* __restrict__ valid_lens,
    const float* __restrict__ values, float* __restrict__ out)
{
  __shared__ unsigned short AtL[16][136];
  __shared__ unsigned int VLu[128][36];
  const int t = threadIdx.x, w = t >> 6, l = t & 63;
  const int b = blockIdx.y;
  const int qt = blockIdx.x & 7;
  const int dt = blockIdx.x >> 3;
  const int lr = l & 15, lk = l >> 4;

  for (int rep = 0; rep < REP_SAV; ++rep) {
    __syncthreads();                       // prev rep done reading AtL/VLu
    {
      const int q_l = t >> 4, k8 = (t & 15) * 8;
      const size_t base = ((size_t)(b * Qn) + qt * 16 + q_l) * Kn + k8;
      float s[8] = {0.f, 0.f, 0.f, 0.f, 0.f, 0.f, 0.f, 0.f};
      #pragma unroll
      for (int p = 0; p < 8; ++p) {
        float4 a0 = *(const float4*)(Sp + base + (size_t)p * 262144);
        float4 a1 = *(const float4*)(Sp + base + (size_t)p * 262144 + 4);
        s[0] += a0.x; s[1] += a0.y; s[2] += a0.z; s[3] += a0.w;
        s[4] += a1.x; s[5] += a1.y; s[6] += a1.z; s[7] += a1.w;
      }
      const int vlen = valid_lens[b];
      bool ok[8];
      float m = NEGV;
      #pragma unroll
      for (int j = 0; j < 8; ++j) {
        ok[j] = (k8 + j) < vlen;
        if (ok[j]) m = fmaxf(m, s[j]);
      }
      #pragma unroll
      for (int xm = 8; xm >= 1; xm >>= 1) m = fmaxf(m, __shfl_xor(m, xm));
      float e[8], sum = 0.f;
      #pragma unroll
      for (int j = 0; j < 8; ++j) {
        e[j] = ok[j] ? exp2_hw((s[j] - m) * 1.44269504f) : 0.f;
        sum += e[j];
      }
      #pragma unroll
      for (int xm = 8; xm >= 1; xm >>= 1) sum += __shfl_xor(sum, xm);
      float inv = rcp_hw(sum);
      ushort4 o0 = {f2bf(e[0] * inv), f2bf(e[1] * inv), f2bf(e[2] * inv), f2bf(e[3] * inv)};
      ushort4 o1 = {f2bf(e[4] * inv), f2bf(e[5] * inv), f2bf(e[6] * inv), f2bf(e[7] * inv)};
      *(ushort4*)&AtL[q_l][k8] = o0;
      *(ushort4*)&AtL[q_l][k8 + 4] = o1;
    }
    __syncthreads();

    const int kread = t & 15, dread = (t >> 4) & 15;
    f32x4 acc[2];
    acc[0] = (f32x4)0.f; acc[1] = (f32x4)0.f;
    #pragma unroll
    for (int k0 = 0; k0 < Kn; k0 += 64) {
      if (k0) __syncthreads();
      #pragma unroll
      for (int j = 0; j < 4; ++j) {
        int k2 = kread + 16 * (j & 1);
        int d4 = dread + 16 * (j >> 1);
        const float* vp = values + ((size_t)(b * Kn) + k0 + 2 * k2) * Dn + dt * 128 + d4 * 4;
        float4 v0 = *(const float4*)(vp);
        float4 v1 = *(const float4*)(vp + Dn);
        VLu[d4 * 4 + 0][k2] = pack2bf(v0.x, v1.x);
        VLu[d4 * 4 + 1][k2] = pack2bf(v0.y, v1.y);
        VLu[d4 * 4 + 2][k2] = pack2bf(v0.z, v1.z);
        VLu[d4 * 4 + 3][k2] = pack2bf(v0.w, v1.w);
      }
      __syncthreads();
      #pragma unroll
      for (int ks = 0; ks < 2; ++ks) {
        s16x8 af = *(const s16x8*)&AtL[lr][k0 + ks * 32 + lk * 8];
        #pragma unroll
        for (int nn = 0; nn < 2; ++nn) {
          s16x8 bv = *(const s16x8*)&VLu[w * 32 + nn * 16 + lr][ks * 16 + lk * 4];
          acc[nn] = __builtin_amdgcn_mfma_f32_16x16x32_bf16(af, bv, acc[nn], 0, 0, 0);
        }
      }
    }
    #pragma unroll
    for (int nn = 0; nn < 2; ++nn)
      #pragma unroll
      for (int r = 0; r < 4; ++r) {
        int q = qt * 16 + lk * 4 + r;
        int d = dt * 128 + w * 32 + nn * 16 + lr;
        out[((size_t)(b * Qn) + q) * Dn + d] = acc[nn][r];
      }
  }
}

extern "C" void kernel_launch(void* const* d_in, const int* in_sizes, int n_in,
                              void* d_out, int out_size, void* d_ws, size_t ws_size,
                              hipStream_t stream) {
  const float* queries    = (const float*)d_in[0];
  const float* keys       = (const float*)d_in[1];
  const float* values     = (const float*)d_in[2];
  const int*   valid_lens = (const int*)d_in[3];
  const float* Wq         = (const float*)d_in[4];
  const float* Wk         = (const float*)d_in[5];
  const float* wv         = (const float*)d_in[6];
  float* out = (float*)d_out;

  unsigned short* Wt  = (unsigned short*)d_ws;       // 2*512*512 bf16     (1MB)
  unsigned int*   QWp = (unsigned int*)(Wt + 524288);// 2048*512 uint      (4MB)
  unsigned int*   Ekp = QWp + 1048576;               // 16*512*64 uint     (2MB)
  float*          Sp  = (float*)(Ekp + 524288);      // 8*16*128*128 f32   (8MB)

  convert_w<<<128, 256, 0, stream>>>(Wq, Wk, Wt);
  proj_mfma<<<dim3(64, 4), 256, 0, stream>>>(queries, keys, Wt, wv, QWp, Ekp);
  score_kernel<<<512, 256, 0, stream>>>(QWp, Ekp, Sp);
  softmax_av<<<dim3(32, 16), 256, 0, stream>>>(Sp, valid_lens, values, out);
}

// Round 18
// 46.500 us; speedup vs baseline: 4.2690x; 4.2690x over previous
//
#include <hip/hip_runtime.h>

#define Bn 16
#define Qn 128
#define Kn 128
#define Dn 512
#define Hn 512
#define NEGV (-3.0e38f)
// 2*log2(e): exp2(PSCALE*x) == e^{2x}
#define PSCALE 2.8853900817779268f

typedef short s16x8 __attribute__((ext_vector_type(8)));
typedef float f32x4 __attribute__((ext_vector_type(4)));

__device__ __forceinline__ float exp2_hw(float x) {
  float r;
  asm("v_exp_f32 %0, %1" : "=v"(r) : "v"(x));
  return r;
}
__device__ __forceinline__ float rcp_hw(float x) { return __builtin_amdgcn_rcpf(x); }
__device__ __forceinline__ unsigned short f2bf(float f) {   // RNE f32->bf16
  unsigned int u = __float_as_uint(f);
  u += 0x7fff + ((u >> 16) & 1);
  return (unsigned short)(u >> 16);
}
__device__ __forceinline__ unsigned int pack2bf(float lo, float hi) {
  return (unsigned int)f2bf(lo) | ((unsigned int)f2bf(hi) << 16);
}
__device__ __forceinline__ float bfl(unsigned int u) { return __uint_as_float(u << 16); }
__device__ __forceinline__ float bfh(unsigned int u) { return __uint_as_float(u & 0xffff0000u); }

// ---------- K1: W transpose + bf16: Wt[2][512 n][512 k] ----------
__global__ __launch_bounds__(256) void convert_w(
    const float* __restrict__ Wq, const float* __restrict__ Wk,
    unsigned short* __restrict__ Wt)
{
  const int tid = blockIdx.x * 256 + threadIdx.x;     // 0..32767
  const int n = tid & 511, rest = tid >> 9;           // rest 0..63
  const int sel = rest >> 5, k16 = rest & 31;
  const float* W = sel ? Wk : Wq;
  unsigned short o[16];
  #pragma unroll
  for (int i = 0; i < 16; ++i)
    o[i] = f2bf(W[(size_t)(k16 * 16 + i) * Hn + n]);
  unsigned short* dst = Wt + (size_t)sel * 262144 + (size_t)n * 512 + k16 * 16;
  #pragma unroll
  for (int j = 0; j < 4; ++j) *(ushort4*)(dst + j * 4) = *(ushort4*)&o[j * 4];
}

// ---------- K2: projections via bf16 MFMA, BM=64 BN=128 BK=64, grid (64,4) ----------
// q rows -> QWp[q][512 h] uint{bf16 WF, bf16 F}
// k rows -> Ekp[b][512 h][64 k2] uint{bf16 Ek[2k2], bf16 Ek[2k2+1]}
__global__ __launch_bounds__(256) void proj_mfma(
    const float* __restrict__ queries, const float* __restrict__ keys,
    const unsigned short* __restrict__ Wt, const float* __restrict__ wv,
    unsigned int* __restrict__ QWp, unsigned int* __restrict__ Ekp)
{
  __shared__ unsigned short Al[64][72];    // A tile (bf16)
  __shared__ unsigned short Bl[128][72];   // W tile (bf16)
  __shared__ float Tep[64][68];            // k-epilogue transpose chunk
  const int t = threadIdx.x, w = t >> 6, l = t & 63;
  const int wm = w >> 1, wn = w & 1;
  const int rowTile = blockIdx.x;          // 0..63 (64-row tiles)
  const int n0 = blockIdx.y * 128;
  const int R0 = rowTile * 64;
  const bool isQ = rowTile < 32;
  const float* Asrc = isQ ? queries : keys;
  const int rowBase = isQ ? R0 : (R0 - 2048);
  const unsigned short* Wsel = Wt + (isQ ? 0 : 262144);

  f32x4 acc[2][4];
  #pragma unroll
  for (int m = 0; m < 2; ++m)
    #pragma unroll
    for (int n = 0; n < 4; ++n) acc[m][n] = (f32x4)0.f;

  const int lr = l & 15, lk = l >> 4;

  for (int k0 = 0; k0 < Hn; k0 += 64) {
    float4 afr[4];
    ushort4 br[4][2];
    #pragma unroll
    for (int i = 0; i < 4; ++i) {          // A: 64r x 64k f32
      int g = t + 256 * i, r = g >> 4, c4 = g & 15;
      afr[i] = *(const float4*)(Asrc + (size_t)(rowBase + r) * Dn + k0 + c4 * 4);
    }
    #pragma unroll
    for (int i = 0; i < 4; ++i) {          // W: 128n x 64k bf16
      int g = t + 256 * i, r = g >> 3, c = g & 7;
      const unsigned short* p = Wsel + (size_t)(n0 + r) * Hn + k0 + c * 8;
      br[i][0] = *(const ushort4*)p; br[i][1] = *(const ushort4*)(p + 4);
    }
    __syncthreads();
    #pragma unroll
    for (int i = 0; i < 4; ++i) {
      int g = t + 256 * i, r = g >> 4, c4 = g & 15;
      ushort4 o = {f2bf(afr[i].x), f2bf(afr[i].y), f2bf(afr[i].z), f2bf(afr[i].w)};
      *(ushort4*)&Al[r][c4 * 4] = o;
    }
    #pragma unroll
    for (int i = 0; i < 4; ++i) {
      int g = t + 256 * i, r = g >> 3, c = g & 7;
      *(ushort4*)&Bl[r][c * 8] = br[i][0]; *(ushort4*)&Bl[r][c * 8 + 4] = br[i][1];
    }
    __syncthreads();
    #pragma unroll
    for (int ks = 0; ks < 2; ++ks) {
      s16x8 af[2], bf_[4];
      #pragma unroll
      for (int m = 0; m < 2; ++m)
        af[m] = *(const s16x8*)&Al[wm * 32 + m * 16 + lr][ks * 32 + lk * 8];
      #pragma unroll
      for (int n = 0; n < 4; ++n)
        bf_[n] = *(const s16x8*)&Bl[wn * 64 + n * 16 + lr][ks * 32 + lk * 8];
      #pragma unroll
      for (int m = 0; m < 2; ++m)
        #pragma unroll
        for (int n = 0; n < 4; ++n)
          acc[m][n] = __builtin_amdgcn_mfma_f32_16x16x32_bf16(af[m], bf_[n], acc[m][n], 0, 0, 0);
    }
    __syncthreads();
  }

  if (isQ) {
    #pragma unroll
    for (int m = 0; m < 2; ++m)
      #pragma unroll
      for (int n = 0; n < 4; ++n)
        #pragma unroll
        for (int r = 0; r < 4; ++r) {
          int row = R0 + wm * 32 + m * 16 + lk * 4 + r;
          int col = n0 + wn * 64 + n * 16 + lr;      // h
          float a = acc[m][n][r];
          float F  = exp2_hw(-PSCALE * a);           // e^{-2q}
          float WF = -2.f * wv[col] * F;
          QWp[(size_t)row * Hn + col] = pack2bf(WF, F);
        }
  } else {
    const int krow0 = R0 - 2048;             // 0..1984, step 64
    const int bb = krow0 >> 7, kb = krow0 & 127;    // batch, k base (0|64)
    const int hl = t >> 2, kq = (t & 3) * 16;
    #pragma unroll
    for (int hc = 0; hc < 2; ++hc) {         // 64-h chunks; wave wn==hc writes
      __syncthreads();
      if (wn == hc) {
        #pragma unroll
        for (int m = 0; m < 2; ++m)
          #pragma unroll
          for (int n = 0; n < 4; ++n)
            #pragma unroll
            for (int r = 0; r < 4; ++r) {
              int row_l = wm * 32 + m * 16 + lk * 4 + r;   // k local 0..63
              int h_l = n * 16 + lr;                        // h local 0..63
              Tep[h_l][row_l] = exp2_hw(PSCALE * acc[m][n][r]);
            }
      }
      __syncthreads();
      unsigned int* dst = Ekp + (size_t)bb * 32768
                        + (size_t)(n0 + hc * 64 + hl) * 64 + (kb + kq) / 2;
      #pragma unroll
      for (int j = 0; j < 4; ++j) {
        float4 v = *(const float4*)&Tep[hl][kq + j * 4];
        uint2 o = {pack2bf(v.x, v.y), pack2bf(v.z, v.w)};
        *(uint2*)(dst + j * 2) = o;
      }
    }
  }
}

// ---------- helper: 8-k x 2-h score terms ----------
__device__ __forceinline__ void term8(float WF0, float F0, float WF1, float F1,
                                      const float ek0[8], const float ek1[8],
                                      float acc[8]) {
  #pragma unroll
  for (int j = 0; j < 8; ++j) {
    float d0 = F0 + ek0[j];
    float d1 = F1 + ek1[j];
    float num = __builtin_fmaf(WF0, d1, WF1 * d0);
    acc[j] = __builtin_fmaf(num, rcp_hw(d0 * d1), acc[j]);
  }
}

// ---------- K3: score v3 — Ek unpacked ONCE to f32 LDS; packed QW in LDS ----------
// Block = 256 thr (4 waves): (b, hs 64h-chunk, 32 q, 128 k). 512 blocks.
// LDS 40.5KB (EkL 32K f32 + QWLu 8.7K packed) -> 2 blocks/CU resident.
// Inner loop: pure f32 math, 3.25 VALU + 0.5 trans per element.
__global__ __launch_bounds__(256) void score_kernel(
    const unsigned int* __restrict__ QWp, const unsigned int* __restrict__ Ekp,
    float* __restrict__ Sp)
{
  __shared__ float EkL[64][128];           // [h][k] f32; 32B k-stride reads = 2-way free
  __shared__ unsigned int QWLu[32][68];    // [q][h] packed (+4 pad)
  const int id = blockIdx.x;
  const int g = id & 127, qt = id >> 7;
  const int b = g >> 3, hs = g & 7;
  const int t = threadIdx.x, w = t >> 6, l = t & 63;
  const int qp = w * 8 + ((l >> 4) << 1);
  const int ka8 = (l & 15) * 8;

  // ---- stage: load packed, unpack Ek -> f32 LDS (one-time) ----
  {
    const uint4* esrc = (const uint4*)(Ekp + (size_t)b * 32768 + (size_t)hs * 4096);
    uint4 er[4];
    #pragma unroll
    for (int i = 0; i < 4; ++i) er[i] = esrc[t + 256 * i];
    uint4 qr[2];
    #pragma unroll
    for (int i = 0; i < 2; ++i) {
      int lin = t + 256 * i, row = lin >> 4, c4 = lin & 15;
      qr[i] = *(const uint4*)(QWp + (size_t)(b * Qn + qt * 32 + row) * Hn + hs * 64 + c4 * 4);
    }
    #pragma unroll
    for (int i = 0; i < 4; ++i) {
      int lin = t + 256 * i, row = lin >> 4, c4 = lin & 15;  // h row, uint4-col
      const unsigned int u[4] = {er[i].x, er[i].y, er[i].z, er[i].w};
      float f[8];
      #pragma unroll
      for (int p = 0; p < 4; ++p) { f[2 * p] = bfl(u[p]); f[2 * p + 1] = bfh(u[p]); }
      *(float4*)&EkL[row][c4 * 8]     = *(const float4*)&f[0];
      *(float4*)&EkL[row][c4 * 8 + 4] = *(const float4*)&f[4];
    }
    #pragma unroll
    for (int i = 0; i < 2; ++i) {
      int lin = t + 256 * i, row = lin >> 4, c4 = lin & 15;
      *(uint4*)&QWLu[row][c4 * 4] = qr[i];
    }
  }
  __syncthreads();

  float acc0[8], acc1[8];
  #pragma unroll
  for (int j = 0; j < 8; ++j) { acc0[j] = 0.f; acc1[j] = 0.f; }

  #pragma unroll 4
  for (int hb = 0; hb < 32; ++hb) {        // 2 h per iter
    float ek0[8], ek1[8];
    *(float4*)&ek0[0] = *(const float4*)&EkL[2 * hb][ka8];
    *(float4*)&ek0[4] = *(const float4*)&EkL[2 * hb][ka8 + 4];
    *(float4*)&ek1[0] = *(const float4*)&EkL[2 * hb + 1][ka8];
    *(float4*)&ek1[4] = *(const float4*)&EkL[2 * hb + 1][ka8 + 4];
    uint2 qa = *(const uint2*)&QWLu[qp][hb * 2];       // {h even, h odd} q
    uint2 qb = *(const uint2*)&QWLu[qp + 1][hb * 2];   // q+1
    term8(bfl(qa.x), bfh(qa.x), bfl(qa.y), bfh(qa.y), ek0, ek1, acc0);
    term8(bfl(qb.x), bfh(qb.x), bfl(qb.y), bfh(qb.y), ek0, ek1, acc1);
  }

  const int q = qt * 32 + qp;
  size_t sb = (((size_t)hs * Bn + b) * Qn + q) * Kn;
  *(float4*)(Sp + sb + ka8)          = (float4){acc0[0], acc0[1], acc0[2], acc0[3]};
  *(float4*)(Sp + sb + ka8 + 4)      = (float4){acc0[4], acc0[5], acc0[6], acc0[7]};
  *(float4*)(Sp + sb + Kn + ka8)     = (float4){acc1[0], acc1[1], acc1[2], acc1[3]};
  *(float4*)(Sp + sb + Kn + ka8 + 4) = (float4){acc1[4], acc1[5], acc1[6], acc1[7]};
}

// ---------- K4: fused softmax + AV, grid (8qt x 4dt, 16b) = 512 blocks ----------
__global__ __launch_bounds__(256) void softmax_av(
    const float* __restrict__ Sp, const int* __restrict__ valid_lens,
    const float* __restrict__ values, float* __restrict__ out)
{
  __shared__ unsigned short AtL[16][136];  // 16 q x 128 k bf16
  __shared__ unsigned int VLu[128][36];    // [d 128][k2 32] u32 = {bf16 k, k+1}
  const int t = threadIdx.x, w = t >> 6, l = t & 63;
  const int b = blockIdx.y;
  const int qt = blockIdx.x & 7;           // 16-q tile
  const int dt = blockIdx.x >> 3;          // 0..3 (128-d tile)
  const int lr = l & 15, lk = l >> 4;

  // ---- Phase A: softmax (thread: q = t>>4, 8 k at (t&15)*8) ----
  {
    const int q_l = t >> 4, k8 = (t & 15) * 8;
    const size_t base = ((size_t)(b * Qn) + qt * 16 + q_l) * Kn + k8;
    float s[8] = {0.f, 0.f, 0.f, 0.f, 0.f, 0.f, 0.f, 0.f};
    #pragma unroll
    for (int p = 0; p < 8; ++p) {
      float4 a0 = *(const float4*)(Sp + base + (size_t)p * 262144);
      float4 a1 = *(const float4*)(Sp + base + (size_t)p * 262144 + 4);
      s[0] += a0.x; s[1] += a0.y; s[2] += a0.z; s[3] += a0.w;
      s[4] += a1.x; s[5] += a1.y; s[6] += a1.z; s[7] += a1.w;
    }
    const int vlen = valid_lens[b];
    bool ok[8];
    float m = NEGV;
    #pragma unroll
    for (int j = 0; j < 8; ++j) {
      ok[j] = (k8 + j) < vlen;
      if (ok[j]) m = fmaxf(m, s[j]);
    }
    #pragma unroll
    for (int xm = 8; xm >= 1; xm >>= 1) m = fmaxf(m, __shfl_xor(m, xm));
    float e[8], sum = 0.f;
    #pragma unroll
    for (int j = 0; j < 8; ++j) {
      e[j] = ok[j] ? exp2_hw((s[j] - m) * 1.44269504f) : 0.f;
      sum += e[j];
    }
    #pragma unroll
    for (int xm = 8; xm >= 1; xm >>= 1) sum += __shfl_xor(sum, xm);
    float inv = rcp_hw(sum);
    ushort4 o0 = {f2bf(e[0] * inv), f2bf(e[1] * inv), f2bf(e[2] * inv), f2bf(e[3] * inv)};
    ushort4 o1 = {f2bf(e[4] * inv), f2bf(e[5] * inv), f2bf(e[6] * inv), f2bf(e[7] * inv)};
    *(ushort4*)&AtL[q_l][k8] = o0;
    *(ushort4*)&AtL[q_l][k8 + 4] = o1;
  }
  __syncthreads();

  // ---- Phase B: AV for fixed dt. Wave w owns d cols [w*32, w*32+32) ----
  const int kread = t & 15, dread = (t >> 4) & 15;
  f32x4 acc[2];
  acc[0] = (f32x4)0.f; acc[1] = (f32x4)0.f;
  #pragma unroll
  for (int k0 = 0; k0 < Kn; k0 += 64) {
    if (k0) __syncthreads();
    #pragma unroll
    for (int j = 0; j < 4; ++j) {
      int k2 = kread + 16 * (j & 1);
      int d4 = dread + 16 * (j >> 1);
      const float* vp = values + ((size_t)(b * Kn) + k0 + 2 * k2) * Dn + dt * 128 + d4 * 4;
      float4 v0 = *(const float4*)(vp);
      float4 v1 = *(const float4*)(vp + Dn);
      VLu[d4 * 4 + 0][k2] = pack2bf(v0.x, v1.x);
      VLu[d4 * 4 + 1][k2] = pack2bf(v0.y, v1.y);
      VLu[d4 * 4 + 2][k2] = pack2bf(v0.z, v1.z);
      VLu[d4 * 4 + 3][k2] = pack2bf(v0.w, v1.w);
    }
    __syncthreads();
    #pragma unroll
    for (int ks = 0; ks < 2; ++ks) {
      s16x8 af = *(const s16x8*)&AtL[lr][k0 + ks * 32 + lk * 8];
      #pragma unroll
      for (int nn = 0; nn < 2; ++nn) {
        s16x8 bv = *(const s16x8*)&VLu[w * 32 + nn * 16 + lr][ks * 16 + lk * 4];
        acc[nn] = __builtin_amdgcn_mfma_f32_16x16x32_bf16(af, bv, acc[nn], 0, 0, 0);
      }
    }
  }
  #pragma unroll
  for (int nn = 0; nn < 2; ++nn)
    #pragma unroll
    for (int r = 0; r < 4; ++r) {
      int q = qt * 16 + lk * 4 + r;
      int d = dt * 128 + w * 32 + nn * 16 + lr;
      out[((size_t)(b * Qn) + q) * Dn + d] = acc[nn][r];
    }
}

extern "C" void kernel_launch(void* const* d_in, const int* in_sizes, int n_in,
                              void* d_out, int out_size, void* d_ws, size_t ws_size,
                              hipStream_t stream) {
  const float* queries    = (const float*)d_in[0];
  const float* keys       = (const float*)d_in[1];
  const float* values     = (const float*)d_in[2];
  const int*   valid_lens = (const int*)d_in[3];
  const float* Wq         = (const float*)d_in[4];
  const float* Wk         = (const float*)d_in[5];
  const float* wv         = (const float*)d_in[6];
  float* out = (float*)d_out;

  unsigned short* Wt  = (unsigned short*)d_ws;       // 2*512*512 bf16     (1MB)
  unsigned int*   QWp = (unsigned int*)(Wt + 524288);// 2048*512 uint      (4MB)
  unsigned int*   Ekp = QWp + 1048576;               // 16*512*64 uint     (2MB)
  float*          Sp  = (float*)(Ekp + 524288);      // 8*16*128*128 f32   (8MB)

  convert_w<<<128, 256, 0, stream>>>(Wq, Wk, Wt);
  proj_mfma<<<dim3(64, 4), 256, 0, stream>>>(queries, keys, Wt, wv, QWp, Ekp);
  score_kernel<<<512, 256, 0, stream>>>(QWp, Ekp, Sp);
  softmax_av<<<dim3(32, 16), 256, 0, stream>>>(Sp, valid_lens, values, out);
}

// Round 19
// 46.019 us; speedup vs baseline: 4.3136x; 1.0104x over previous
//
#include <hip/hip_runtime.h>

#define Bn 16
#define Qn 128
#define Kn 128
#define Dn 512
#define Hn 512
#define NEGV (-3.0e38f)
// 2*log2(e): exp2(PSCALE*x) == e^{2x}
#define PSCALE 2.8853900817779268f

typedef short s16x8 __attribute__((ext_vector_type(8)));
typedef float f32x4 __attribute__((ext_vector_type(4)));

__device__ __forceinline__ float exp2_hw(float x) {
  float r;
  asm("v_exp_f32 %0, %1" : "=v"(r) : "v"(x));
  return r;
}
__device__ __forceinline__ float rcp_hw(float x) { return __builtin_amdgcn_rcpf(x); }
__device__ __forceinline__ unsigned short f2bf(float f) {   // RNE f32->bf16
  unsigned int u = __float_as_uint(f);
  u += 0x7fff + ((u >> 16) & 1);
  return (unsigned short)(u >> 16);
}
__device__ __forceinline__ unsigned int pack2bf(float lo, float hi) {
  return (unsigned int)f2bf(lo) | ((unsigned int)f2bf(hi) << 16);
}
__device__ __forceinline__ float bfl(unsigned int u) { return __uint_as_float(u << 16); }
__device__ __forceinline__ float bfh(unsigned int u) { return __uint_as_float(u & 0xffff0000u); }

// ---------- K1 v2: W transpose + bf16, coalesced via LDS 64x64 tile ----------
// Wt[2][512 n][512 k]. 128 blocks: sel (2) x kt (8) x nt (8).
__global__ __launch_bounds__(256) void convert_w(
    const float* __restrict__ Wq, const float* __restrict__ Wk,
    unsigned short* __restrict__ Wt)
{
  __shared__ float Tl[64][68];
  const int bid = blockIdx.x, t = threadIdx.x;
  const int sel = bid >> 6, tile = bid & 63;
  const int kt = tile >> 3, nt = tile & 7;
  const float* W = sel ? Wk : Wq;

  const int r0 = t >> 4, c4 = (t & 15) * 4;
  #pragma unroll
  for (int p = 0; p < 4; ++p) {            // coalesced row-major read
    int r = r0 + p * 16;                   // k-local
    float4 v = *(const float4*)(W + (size_t)(kt * 64 + r) * Hn + nt * 64 + c4);
    *(float4*)&Tl[r][c4] = v;
  }
  __syncthreads();

  const int n_l = t >> 3, k8 = (t & 7) * 8;
  #pragma unroll
  for (int p = 0; p < 2; ++p) {            // coalesced k-contiguous write
    int n = n_l + p * 32;
    unsigned short o[8];
    #pragma unroll
    for (int i = 0; i < 8; ++i) o[i] = f2bf(Tl[k8 + i][n]);
    unsigned short* dst = Wt + (size_t)sel * 262144 + (size_t)(nt * 64 + n) * 512 + kt * 64 + k8;
    *(ushort4*)dst = *(const ushort4*)&o[0];
    *(ushort4*)(dst + 4) = *(const ushort4*)&o[4];
  }
}

// ---------- K2: projections via bf16 MFMA, BM=64 BN=128 BK=64, grid (64,4) ----------
// q rows -> QWp[q][512 h] uint{bf16 WF, bf16 F}
// k rows -> Ekp[b][512 h][64 k2] uint{bf16 Ek[2k2], bf16 Ek[2k2+1]}
__global__ __launch_bounds__(256) void proj_mfma(
    const float* __restrict__ queries, const float* __restrict__ keys,
    const unsigned short* __restrict__ Wt, const float* __restrict__ wv,
    unsigned int* __restrict__ QWp, unsigned int* __restrict__ Ekp)
{
  __shared__ unsigned short Al[64][72];    // A tile (bf16)
  __shared__ unsigned short Bl[128][72];   // W tile (bf16)
  __shared__ float Tep[64][68];            // k-epilogue transpose chunk
  const int t = threadIdx.x, w = t >> 6, l = t & 63;
  const int wm = w >> 1, wn = w & 1;
  const int rowTile = blockIdx.x;          // 0..63 (64-row tiles)
  const int n0 = blockIdx.y * 128;
  const int R0 = rowTile * 64;
  const bool isQ = rowTile < 32;
  const float* Asrc = isQ ? queries : keys;
  const int rowBase = isQ ? R0 : (R0 - 2048);
  const unsigned short* Wsel = Wt + (isQ ? 0 : 262144);

  f32x4 acc[2][4];
  #pragma unroll
  for (int m = 0; m < 2; ++m)
    #pragma unroll
    for (int n = 0; n < 4; ++n) acc[m][n] = (f32x4)0.f;

  const int lr = l & 15, lk = l >> 4;

  for (int k0 = 0; k0 < Hn; k0 += 64) {
    float4 afr[4];
    ushort4 br[4][2];
    #pragma unroll
    for (int i = 0; i < 4; ++i) {          // A: 64r x 64k f32
      int g = t + 256 * i, r = g >> 4, c4 = g & 15;
      afr[i] = *(const float4*)(Asrc + (size_t)(rowBase + r) * Dn + k0 + c4 * 4);
    }
    #pragma unroll
    for (int i = 0; i < 4; ++i) {          // W: 128n x 64k bf16
      int g = t + 256 * i, r = g >> 3, c = g & 7;
      const unsigned short* p = Wsel + (size_t)(n0 + r) * Hn + k0 + c * 8;
      br[i][0] = *(const ushort4*)p; br[i][1] = *(const ushort4*)(p + 4);
    }
    __syncthreads();
    #pragma unroll
    for (int i = 0; i < 4; ++i) {
      int g = t + 256 * i, r = g >> 4, c4 = g & 15;
      ushort4 o = {f2bf(afr[i].x), f2bf(afr[i].y), f2bf(afr[i].z), f2bf(afr[i].w)};
      *(ushort4*)&Al[r][c4 * 4] = o;
    }
    #pragma unroll
    for (int i = 0; i < 4; ++i) {
      int g = t + 256 * i, r = g >> 3, c = g & 7;
      *(ushort4*)&Bl[r][c * 8] = br[i][0]; *(ushort4*)&Bl[r][c * 8 + 4] = br[i][1];
    }
    __syncthreads();
    #pragma unroll
    for (int ks = 0; ks < 2; ++ks) {
      s16x8 af[2], bf_[4];
      #pragma unroll
      for (int m = 0; m < 2; ++m)
        af[m] = *(const s16x8*)&Al[wm * 32 + m * 16 + lr][ks * 32 + lk * 8];
      #pragma unroll
      for (int n = 0; n < 4; ++n)
        bf_[n] = *(const s16x8*)&Bl[wn * 64 + n * 16 + lr][ks * 32 + lk * 8];
      #pragma unroll
      for (int m = 0; m < 2; ++m)
        #pragma unroll
        for (int n = 0; n < 4; ++n)
          acc[m][n] = __builtin_amdgcn_mfma_f32_16x16x32_bf16(af[m], bf_[n], acc[m][n], 0, 0, 0);
    }
    __syncthreads();
  }

  if (isQ) {
    #pragma unroll
    for (int m = 0; m < 2; ++m)
      #pragma unroll
      for (int n = 0; n < 4; ++n)
        #pragma unroll
        for (int r = 0; r < 4; ++r) {
          int row = R0 + wm * 32 + m * 16 + lk * 4 + r;
          int col = n0 + wn * 64 + n * 16 + lr;      // h
          float a = acc[m][n][r];
          float F  = exp2_hw(-PSCALE * a);           // e^{-2q}
          float WF = -2.f * wv[col] * F;
          QWp[(size_t)row * Hn + col] = pack2bf(WF, F);
        }
  } else {
    const int krow0 = R0 - 2048;             // 0..1984, step 64
    const int bb = krow0 >> 7, kb = krow0 & 127;    // batch, k base (0|64)
    const int hl = t >> 2, kq = (t & 3) * 16;
    #pragma unroll
    for (int hc = 0; hc < 2; ++hc) {         // 64-h chunks; wave wn==hc writes
      __syncthreads();
      if (wn == hc) {
        #pragma unroll
        for (int m = 0; m < 2; ++m)
          #pragma unroll
          for (int n = 0; n < 4; ++n)
            #pragma unroll
            for (int r = 0; r < 4; ++r) {
              int row_l = wm * 32 + m * 16 + lk * 4 + r;   // k local 0..63
              int h_l = n * 16 + lr;                        // h local 0..63
              Tep[h_l][row_l] = exp2_hw(PSCALE * acc[m][n][r]);
            }
      }
      __syncthreads();
      unsigned int* dst = Ekp + (size_t)bb * 32768
                        + (size_t)(n0 + hc * 64 + hl) * 64 + (kb + kq) / 2;
      #pragma unroll
      for (int j = 0; j < 4; ++j) {
        float4 v = *(const float4*)&Tep[hl][kq + j * 4];
        uint2 o = {pack2bf(v.x, v.y), pack2bf(v.z, v.w)};
        *(uint2*)(dst + j * 2) = o;
      }
    }
  }
}

// ---------- helper: 8-k x 2-h score terms ----------
__device__ __forceinline__ void term8(float WF0, float F0, float WF1, float F1,
                                      const float ek0[8], const float ek1[8],
                                      float acc[8]) {
  #pragma unroll
  for (int j = 0; j < 8; ++j) {
    float d0 = F0 + ek0[j];
    float d1 = F1 + ek1[j];
    float num = __builtin_fmaf(WF0, d1, WF1 * d0);
    acc[j] = __builtin_fmaf(num, rcp_hw(d0 * d1), acc[j]);
  }
}

// ---------- K3: score v3 — Ek unpacked ONCE to f32 LDS; packed QW in LDS ----------
__global__ __launch_bounds__(256) void score_kernel(
    const unsigned int* __restrict__ QWp, const unsigned int* __restrict__ Ekp,
    float* __restrict__ Sp)
{
  __shared__ float EkL[64][128];           // [h][k] f32
  __shared__ unsigned int QWLu[32][68];    // [q][h] packed (+4 pad)
  const int id = blockIdx.x;
  const int g = id & 127, qt = id >> 7;
  const int b = g >> 3, hs = g & 7;
  const int t = threadIdx.x, w = t >> 6, l = t & 63;
  const int qp = w * 8 + ((l >> 4) << 1);
  const int ka8 = (l & 15) * 8;

  {
    const uint4* esrc = (const uint4*)(Ekp + (size_t)b * 32768 + (size_t)hs * 4096);
    uint4 er[4];
    #pragma unroll
    for (int i = 0; i < 4; ++i) er[i] = esrc[t + 256 * i];
    uint4 qr[2];
    #pragma unroll
    for (int i = 0; i < 2; ++i) {
      int lin = t + 256 * i, row = lin >> 4, c4 = lin & 15;
      qr[i] = *(const uint4*)(QWp + (size_t)(b * Qn + qt * 32 + row) * Hn + hs * 64 + c4 * 4);
    }
    #pragma unroll
    for (int i = 0; i < 4; ++i) {
      int lin = t + 256 * i, row = lin >> 4, c4 = lin & 15;
      const unsigned int u[4] = {er[i].x, er[i].y, er[i].z, er[i].w};
      float f[8];
      #pragma unroll
      for (int p = 0; p < 4; ++p) { f[2 * p] = bfl(u[p]); f[2 * p + 1] = bfh(u[p]); }
      *(float4*)&EkL[row][c4 * 8]     = *(const float4*)&f[0];
      *(float4*)&EkL[row][c4 * 8 + 4] = *(const float4*)&f[4];
    }
    #pragma unroll
    for (int i = 0; i < 2; ++i) {
      int lin = t + 256 * i, row = lin >> 4, c4 = lin & 15;
      *(uint4*)&QWLu[row][c4 * 4] = qr[i];
    }
  }
  __syncthreads();

  float acc0[8], acc1[8];
  #pragma unroll
  for (int j = 0; j < 8; ++j) { acc0[j] = 0.f; acc1[j] = 0.f; }

  #pragma unroll 4
  for (int hb = 0; hb < 32; ++hb) {        // 2 h per iter
    float ek0[8], ek1[8];
    *(float4*)&ek0[0] = *(const float4*)&EkL[2 * hb][ka8];
    *(float4*)&ek0[4] = *(const float4*)&EkL[2 * hb][ka8 + 4];
    *(float4*)&ek1[0] = *(const float4*)&EkL[2 * hb + 1][ka8];
    *(float4*)&ek1[4] = *(const float4*)&EkL[2 * hb + 1][ka8 + 4];
    uint2 qa = *(const uint2*)&QWLu[qp][hb * 2];
    uint2 qb = *(const uint2*)&QWLu[qp + 1][hb * 2];
    term8(bfl(qa.x), bfh(qa.x), bfl(qa.y), bfh(qa.y), ek0, ek1, acc0);
    term8(bfl(qb.x), bfh(qb.x), bfl(qb.y), bfh(qb.y), ek0, ek1, acc1);
  }

  const int q = qt * 32 + qp;
  size_t sb = (((size_t)hs * Bn + b) * Qn + q) * Kn;
  *(float4*)(Sp + sb + ka8)          = (float4){acc0[0], acc0[1], acc0[2], acc0[3]};
  *(float4*)(Sp + sb + ka8 + 4)      = (float4){acc0[4], acc0[5], acc0[6], acc0[7]};
  *(float4*)(Sp + sb + Kn + ka8)     = (float4){acc1[0], acc1[1], acc1[2], acc1[3]};
  *(float4*)(Sp + sb + Kn + ka8 + 4) = (float4){acc1[4], acc1[5], acc1[6], acc1[7]};
}

// ---------- K4: fused softmax + AV, grid (8qt x 4dt, 16b) = 512 blocks ----------
__global__ __launch_bounds__(256) void softmax_av(
    const float* __restrict__ Sp, const int* __restrict__ valid_lens,
    const float* __restrict__ values, float* __restrict__ out)
{
  __shared__ unsigned short AtL[16][136];  // 16 q x 128 k bf16
  __shared__ unsigned int VLu[128][36];    // [d 128][k2 32] u32 = {bf16 k, k+1}
  const int t = threadIdx.x, w = t >> 6, l = t & 63;
  const int b = blockIdx.y;
  const int qt = blockIdx.x & 7;           // 16-q tile
  const int dt = blockIdx.x >> 3;          // 0..3 (128-d tile)
  const int lr = l & 15, lk = l >> 4;

  // ---- Phase A: softmax ----
  {
    const int q_l = t >> 4, k8 = (t & 15) * 8;
    const size_t base = ((size_t)(b * Qn) + qt * 16 + q_l) * Kn + k8;
    float s[8] = {0.f, 0.f, 0.f, 0.f, 0.f, 0.f, 0.f, 0.f};
    #pragma unroll
    for (int p = 0; p < 8; ++p) {
      float4 a0 = *(const float4*)(Sp + base + (size_t)p * 262144);
      float4 a1 = *(const float4*)(Sp + base + (size_t)p * 262144 + 4);
      s[0] += a0.x; s[1] += a0.y; s[2] += a0.z; s[3] += a0.w;
      s[4] += a1.x; s[5] += a1.y; s[6] += a1.z; s[7] += a1.w;
    }
    const int vlen = valid_lens[b];
    bool ok[8];
    float m = NEGV;
    #pragma unroll
    for (int j = 0; j < 8; ++j) {
      ok[j] = (k8 + j) < vlen;
      if (ok[j]) m = fmaxf(m, s[j]);
    }
    #pragma unroll
    for (int xm = 8; xm >= 1; xm >>= 1) m = fmaxf(m, __shfl_xor(m, xm));
    float e[8], sum = 0.f;
    #pragma unroll
    for (int j = 0; j < 8; ++j) {
      e[j] = ok[j] ? exp2_hw((s[j] - m) * 1.44269504f) : 0.f;
      sum += e[j];
    }
    #pragma unroll
    for (int xm = 8; xm >= 1; xm >>= 1) sum += __shfl_xor(sum, xm);
    float inv = rcp_hw(sum);
    ushort4 o0 = {f2bf(e[0] * inv), f2bf(e[1] * inv), f2bf(e[2] * inv), f2bf(e[3] * inv)};
    ushort4 o1 = {f2bf(e[4] * inv), f2bf(e[5] * inv), f2bf(e[6] * inv), f2bf(e[7] * inv)};
    *(ushort4*)&AtL[q_l][k8] = o0;
    *(ushort4*)&AtL[q_l][k8 + 4] = o1;
  }
  __syncthreads();

  // ---- Phase B: AV for fixed dt ----
  const int kread = t & 15, dread = (t >> 4) & 15;
  f32x4 acc[2];
  acc[0] = (f32x4)0.f; acc[1] = (f32x4)0.f;
  #pragma unroll
  for (int k0 = 0; k0 < Kn; k0 += 64) {
    if (k0) __syncthreads();
    #pragma unroll
    for (int j = 0; j < 4; ++j) {
      int k2 = kread + 16 * (j & 1);
      int d4 = dread + 16 * (j >> 1);
      const float* vp = values + ((size_t)(b * Kn) + k0 + 2 * k2) * Dn + dt * 128 + d4 * 4;
      float4 v0 = *(const float4*)(vp);
      float4 v1 = *(const float4*)(vp + Dn);
      VLu[d4 * 4 + 0][k2] = pack2bf(v0.x, v1.x);
      VLu[d4 * 4 + 1][k2] = pack2bf(v0.y, v1.y);
      VLu[d4 * 4 + 2][k2] = pack2bf(v0.z, v1.z);
      VLu[d4 * 4 + 3][k2] = pack2bf(v0.w, v1.w);
    }
    __syncthreads();
    #pragma unroll
    for (int ks = 0; ks < 2; ++ks) {
      s16x8 af = *(const s16x8*)&AtL[lr][k0 + ks * 32 + lk * 8];
      #pragma unroll
      for (int nn = 0; nn < 2; ++nn) {
        s16x8 bv = *(const s16x8*)&VLu[w * 32 + nn * 16 + lr][ks * 16 + lk * 4];
        acc[nn] = __builtin_amdgcn_mfma_f32_16x16x32_bf16(af, bv, acc[nn], 0, 0, 0);
      }
    }
  }
  #pragma unroll
  for (int nn = 0; nn < 2; ++nn)
    #pragma unroll
    for (int r = 0; r < 4; ++r) {
      int q = qt * 16 + lk * 4 + r;
      int d = dt * 128 + w * 32 + nn * 16 + lr;
      out[((size_t)(b * Qn) + q) * Dn + d] = acc[nn][r];
    }
}

extern "C" void kernel_launch(void* const* d_in, const int* in_sizes, int n_in,
                              void* d_out, int out_size, void* d_ws, size_t ws_size,
                              hipStream_t stream) {
  const float* queries    = (const float*)d_in[0];
  const float* keys       = (const float*)d_in[1];
  const float* values     = (const float*)d_in[2];
  const int*   valid_lens = (const int*)d_in[3];
  const float* Wq         = (const float*)d_in[4];
  const float* Wk         = (const float*)d_in[5];
  const float* wv         = (const float*)d_in[6];
  float* out = (float*)d_out;

  unsigned short* Wt  = (unsigned short*)d_ws;       // 2*512*512 bf16     (1MB)
  unsigned int*   QWp = (unsigned int*)(Wt + 524288);// 2048*512 uint      (4MB)
  unsigned int*   Ekp = QWp + 1048576;               // 16*512*64 uint     (2MB)
  float*          Sp  = (float*)(Ekp + 524288);      // 8*16*128*128 f32   (8MB)

  convert_w<<<128, 256, 0, stream>>>(Wq, Wk, Wt);
  proj_mfma<<<dim3(64, 4), 256, 0, stream>>>(queries, keys, Wt, wv, QWp, Ekp);
  score_kernel<<<512, 256, 0, stream>>>(QWp, Ekp, Sp);
  softmax_av<<<dim3(32, 16), 256, 0, stream>>>(Sp, valid_lens, values, out);
}